// Round 4
// baseline (116.352 us; speedup 1.0000x reference)
//
#include <hip/hip_runtime.h>

#define NB 4096
#define NC 8192

// One wave per (row, matrix). Each iteration covers 512 elements:
// lane handles two float4 quads per array (8 elements), 4 loads/iter,
// software-pipelined 2 deep (8 loads in flight per wave).
//  - BCE: one v_log_f32 per 8 elements: log2(prod |s+t-1|) * ln2
//  - top-6: one ballot per iter on lane's max-of-8 vs exact running
//    6th-max threshold; rare slow path does readlane inserts.
__global__ __launch_bounds__(256) void row_stats(
    const float* __restrict__ tk_s, const float* __restrict__ g_s,
    const float* __restrict__ tk_t, const float* __restrict__ g_t,
    const float* __restrict__ conf, float* __restrict__ ws) {
  const int lane = threadIdx.x & 63;
  const int wave = threadIdx.x >> 6;
  const int row  = (blockIdx.x << 2) + wave;
  const int mat  = blockIdx.y;

  const float4* S4 = reinterpret_cast<const float4*>(
      (mat ? g_s : tk_s) + (size_t)row * NC);
  const float4* T4 = reinterpret_cast<const float4*>(
      (mat ? g_t : tk_t) + (size_t)row * NC);

  // wave-uniform shared top-6 (desc). keys = f32 bits (scores>0 -> monotonic)
  unsigned lk0=0,lk1=0,lk2=0,lk3=0,lk4=0,lk5=0;
  unsigned lp0=0,lp1=0,lp2=0,lp3=0,lp4=0,lp5=0;
  float bl2 = 0.0f;             // sum log2(arg); bce_row_sum = -bl2*ln2
  unsigned tseed;

  // ---- 2-deep, 4-wide prefetch ----
  float4 sa0 = S4[lane],       sb0 = S4[64 + lane];
  float4 ta0 = T4[lane],       tb0 = T4[64 + lane];
  float4 sa1 = S4[128 + lane], sb1 = S4[192 + lane];
  float4 ta1 = T4[128 + lane], tb1 = T4[192 + lane];

  {  // seed: min over 8 disjoint 8-lane-group maxes <= row 6th-max
    float m8 = fmaxf(fmaxf(fmaxf(sa0.x, sa0.y), fmaxf(sa0.z, sa0.w)),
                     fmaxf(fmaxf(sb0.x, sb0.y), fmaxf(sb0.z, sb0.w)));
    m8 = fmaxf(m8, __shfl_xor(m8, 1));
    m8 = fmaxf(m8, __shfl_xor(m8, 2));
    m8 = fmaxf(m8, __shfl_xor(m8, 4));
    m8 = fminf(m8, __shfl_xor(m8, 8));
    m8 = fminf(m8, __shfl_xor(m8, 16));
    m8 = fminf(m8, __shfl_xor(m8, 32));
    tseed = __float_as_uint(m8) - 1u;  // admit equality under strict >
  }

#define INS(KJ, PJ) { if (ck_ > KJ) { unsigned tk_ = KJ, tp_ = PJ;        \
    KJ = ck_; PJ = cp_; ck_ = tk_; cp_ = tp_; } }
#define TRY(KB, QW, CE) { unsigned key_ =                                 \
      (unsigned)__builtin_amdgcn_readlane((int)(KB), l_);                 \
    if (key_ > lk5) {                                                     \
      unsigned ck_ = key_;                                                \
      unsigned cp_ = ((unsigned)(CE) << 1) |                              \
                     (unsigned)((QW >> l_) & 1ull);                       \
      INS(lk0, lp0) INS(lk1, lp1) INS(lk2, lp2)                           \
      INS(lk3, lp3) INS(lk4, lp4) INS(lk5, lp5)                           \
    } }

  auto process = [&](float4 sa, float4 sb, float4 ta, float4 tb, int i) {
    // BCE: arg_e = |s_e + t_e - 1|, one log per 8 elements
    float a0 = sa.x + ta.x - 1.0f, a1 = sa.y + ta.y - 1.0f;
    float a2 = sa.z + ta.z - 1.0f, a3 = sa.w + ta.w - 1.0f;
    float a4 = sb.x + tb.x - 1.0f, a5 = sb.y + tb.y - 1.0f;
    float a6 = sb.z + tb.z - 1.0f, a7 = sb.w + tb.w - 1.0f;
    float pr = ((fabsf(a0) * fabsf(a1)) * (fabsf(a2) * fabsf(a3))) *
               ((fabsf(a4) * fabsf(a5)) * (fabsf(a6) * fabsf(a7)));
    bl2 += __log2f(pr);
    // top-k filter: one ballot per lane-octet
    float m8 = fmaxf(fmaxf(fmaxf(sa.x, sa.y), fmaxf(sa.z, sa.w)),
                     fmaxf(fmaxf(sb.x, sb.y), fmaxf(sb.z, sb.w)));
    float thrf = __uint_as_float(lk5 > tseed ? lk5 : tseed);
    unsigned long long m_ = __ballot(m8 > thrf);
    if (m_) {
      unsigned long long q0 = __ballot(ta.x > 0.5f);
      unsigned long long q1 = __ballot(ta.y > 0.5f);
      unsigned long long q2 = __ballot(ta.z > 0.5f);
      unsigned long long q3 = __ballot(ta.w > 0.5f);
      unsigned long long q4 = __ballot(tb.x > 0.5f);
      unsigned long long q5 = __ballot(tb.y > 0.5f);
      unsigned long long q6 = __ballot(tb.z > 0.5f);
      unsigned long long q7 = __ballot(tb.w > 0.5f);
      unsigned kx0 = __float_as_uint(sa.x), kx1 = __float_as_uint(sa.y);
      unsigned kx2 = __float_as_uint(sa.z), kx3 = __float_as_uint(sa.w);
      unsigned kx4 = __float_as_uint(sb.x), kx5 = __float_as_uint(sb.y);
      unsigned kx6 = __float_as_uint(sb.z), kx7 = __float_as_uint(sb.w);
      do {
        int l_ = __ffsll(m_) - 1;
        m_ &= m_ - 1;
        unsigned ca_ = (unsigned)((i * 128 + l_) * 4);
        unsigned cb_ = ca_ + 256u;
        TRY(kx0, q0, ca_)     TRY(kx1, q1, ca_ + 1)
        TRY(kx2, q2, ca_ + 2) TRY(kx3, q3, ca_ + 3)
        TRY(kx4, q4, cb_)     TRY(kx5, q5, cb_ + 1)
        TRY(kx6, q6, cb_ + 2) TRY(kx7, q7, cb_ + 3)
      } while (m_);
    }
  };

  // ---- main loop: 16 iterations of 512 elements, pipelined 2 deep ----
  #pragma unroll 2
  for (int i = 0; i < 14; ++i) {
    int b = (i + 2) * 128 + lane;
    float4 sa2 = S4[b], sb2 = S4[b + 64];
    float4 ta2 = T4[b], tb2 = T4[b + 64];
    process(sa0, sb0, ta0, tb0, i);
    sa0 = sa1; sb0 = sb1; ta0 = ta1; tb0 = tb1;
    sa1 = sa2; sb1 = sb2; ta1 = ta2; tb1 = tb2;
  }
  process(sa0, sb0, ta0, tb0, 14);
  process(sa1, sb1, ta1, tb1, 15);
#undef TRY
#undef INS

  // wave-reduce log2 sum (butterfly)
  #pragma unroll
  for (int off = 32; off > 0; off >>= 1) bl2 += __shfl_xor(bl2, off);

  if (lane == 0) {
    // first <=2 negatives (target bit 0) in descending score order
    float nsum = 0.0f; int cnt = 0;
#define SELN(ki, pi) { if (((pi) & 1u) == 0u && cnt < 2) {                \
      nsum += -__logf(1.0f - __uint_as_float(ki)); cnt++; } }
    SELN(lk0, lp0) SELN(lk1, lp1) SELN(lk2, lp2)
    SELN(lk3, lp3) SELN(lk4, lp4) SELN(lk5, lp5)
#undef SELN
    const int base = mat * NB + row;
    const float ln2 = 0.6931471805599453f;
    ws[base]          = conf[row] * (-bl2 * ln2);
    ws[2 * NB + base] = nsum;
    ws[4 * NB + base] = (float)cnt;
  }
}

// Deterministic single-block reduction + final loss math (1024 threads).
__global__ __launch_bounds__(1024) void finalize_loss(
    const float* __restrict__ ws, float* __restrict__ out) {
  __shared__ float red[6][16];
  const int t = threadIdx.x;
  const int lane = t & 63, w = t >> 6;
  const float4* W4 = reinterpret_cast<const float4*>(ws);
  float a[6];
  #pragma unroll
  for (int j = 0; j < 6; ++j) {
    float4 v = W4[j * (NB / 4) + t];
    a[j] = (v.x + v.y) + (v.z + v.w);
  }
  #pragma unroll
  for (int j = 0; j < 6; ++j) {
    #pragma unroll
    for (int off = 32; off > 0; off >>= 1) a[j] += __shfl_xor(a[j], off);
  }
  if (lane == 0) {
    #pragma unroll
    for (int j = 0; j < 6; ++j) red[j][w] = a[j];
  }
  __syncthreads();
  if (t == 0) {
    float s[6];
    #pragma unroll
    for (int j = 0; j < 6; ++j) {
      float acc = 0.0f;
      for (int u = 0; u < 16; ++u) acc += red[j][u];
      s[j] = acc;
    }
    const float inv = 1.0f / ((float)NB * (float)NC);
    float tk = s[0] * inv + 0.5f * (s[2] / (s[4] + 1e-8f));
    float g  = s[1] * inv + 0.5f * (s[3] / (s[5] + 1e-8f));
    out[0] = 0.6f * tk + 0.4f * g;
    out[1] = tk;
    out[2] = g;
  }
}

extern "C" void kernel_launch(void* const* d_in, const int* in_sizes, int n_in,
                              void* d_out, int out_size, void* d_ws, size_t ws_size,
                              hipStream_t stream) {
  const float* tk_s = (const float*)d_in[0];
  const float* g_s  = (const float*)d_in[1];
  const float* tk_t = (const float*)d_in[2];
  const float* g_t  = (const float*)d_in[3];
  const float* conf = (const float*)d_in[4];
  float* ws  = (float*)d_ws;   // 6*NB floats = 96 KB
  float* out = (float*)d_out;  // 3 floats: total, tk_loss, g_loss

  dim3 grid(NB / 4, 2);        // 4 rows per block (one per wave), 2 matrices
  row_stats<<<grid, 256, 0, stream>>>(tk_s, g_s, tk_t, g_t, conf, ws);
  finalize_loss<<<1, 1024, 0, stream>>>(ws, out);
}